// Round 8
// baseline (90.487 us; speedup 1.0000x reference)
//
#include <hip/hip_runtime.h>
#include <math.h>

// Soft-DTW (DILATE, alpha=1, gamma=0.01), B=64, N=512, F=1, n=511.
// R26 = R25 (4 waves x 2 rows/lane, KCH=16, mailbox lane-conveyor) +
// three issue-slot fixes, each targeting the measured ~30cy/step gap
// between R25 (~84 cy/step inferred) and the issue model (~54):
//  1. STEP2 reorder: nv_hi computed EARLY in the step, the wave_shr1 DPP
//     placed after it. R25 ordered DPP first, reading r1_hi written by
//     the immediately preceding fma -> 2 hazard wait-states per step
//     (gfx9 VALU-write -> DPP-read rule). Now the DPP source is ~9
//     instructions old: zero nops.
//  2. Producer writes 16x ds_write_b32 (was 8x b64 via make_float2):
//     no register-pairing movs.
//  3. Entry lag deepened: w1/w2 wait flag>=2, w3 waits flag>=4. Waves
//     1,2 have identical per-chunk work (consume+produce) so the lag
//     persists and the in-loop fast path (fcur sampled one chunk early,
//     register compare) never blocks; wave3 (no produce, faster) gets
//     extra initial slack so it doesn't re-converge onto wave2's tail
//     and eat 64cy s_sleep quanta every chunk.
//
// Evidence base: per-wave issue cadence ~5cy/instr is hard (R21: 26
// VALU/diag -> 133 cy/diag, zero residual; R23/R24 consistent). Latency
// = instr/step/wave x cadence + exposed stalls. This kernel: 8 VALU/step
// + ~2.5 amortized chunk overhead -> ~54 cy/step target.
//
// Recursion per step s (d=s+2), thread tid owns rows 2tid (lo), 2tid+1 (hi):
//   nv_hi = (dy_hi - dx[s-2tid])^2   + min3(r2_lo, r1_lo, r1_hi)
//   nv_lo = (dy_lo - dx[s+1-2tid])^2 + min3(SH2,  sh1,  r1_lo)
// sh1 = wave_shr1(r1_hi) with lane0 := M[s-1] riding the DPP old operand
// via the lane conveyor: qc loaded once per chunk (lane l = Mbx[16cc+1+l]),
// shifted one lane toward lane0 per step (WAVE_SHL1). Seed R[0][0]=0
// rides r2_lo of tid==0. Invalid cells hold ~INF by construction
// (ulp(1e9)=64 absorbs u^2; R21/R23/R24/R25-proven, absmax=0).
//
// Mailbox: Mbx[I][idx=sigma+2] = wave I lane63 nv_hi after step sigma.
// Producer chunk cc writes idx 16cc+2..16cc+17. Consumer chunk cc
// conveyor-consumes idx 16cc+1..16cc+16 (lanes 16+ junk, never reach
// lane0 within 16 shifts). Prefill idx 0,1 = INF.
// Window: Mdx[512+f]=dx[f] (f in [0,510], pad 0); chunk cc loads 9 f2 at
// f2-idx 256-tid+8cc (floats F..F+17, F=512+16cc-2tid); XHI(k)=win[k],
// XLO(k)=win[k+1]. Lane f2 stride 8B -> 2-way bank aliasing = free.

#define INF_F 1000000000.0f

// wave shift toward higher lanes; lane0 keeps old[lane0] (bound_ctrl=0)
__device__ __forceinline__ float dpp_shr1_old(float x, float oldv){
  int r = __builtin_amdgcn_update_dpp(__float_as_int(oldv), __float_as_int(x),
                                      0x138 /*WAVE_SHR1*/, 0xf, 0xf, false);
  return __int_as_float(r);
}
// wave shift toward lower lanes; lane63 keeps old (junk-tolerant)
__device__ __forceinline__ float dpp_shl1(float x){
  int r = __builtin_amdgcn_update_dpp(__float_as_int(x), __float_as_int(x),
                                      0x130 /*WAVE_SHL1*/, 0xf, 0xf, false);
  return __int_as_float(r);
}
__device__ __forceinline__ float min3f(float a, float b, float c){
  float d;
  asm("v_min3_f32 %0, %1, %2, %3" : "=v"(d) : "v"(a), "v"(b), "v"(c));
  return d;
}
#define PINF(v) asm volatile("" : "+v"(v))
#define PINW18(P) { PINF(P##0); PINF(P##1); PINF(P##2); PINF(P##3); \
  PINF(P##4); PINF(P##5); PINF(P##6); PINF(P##7); PINF(P##8); PINF(P##9); \
  PINF(P##10); PINF(P##11); PINF(P##12); PINF(P##13); PINF(P##14); \
  PINF(P##15); PINF(P##16); PINF(P##17); }

// One diagonal, two cells. QC = conveyor register (lane0 = M[s-1] inject).
// Hazard-free order: nvH early; DPP reads r1_hi (prev step's nvH, ~9
// instructions old) and QC (8 old).
#define STEP2(K, QC, XLO, XHI) { \
  float uH  = dy_hi - (XHI); \
  float mnH = min3f(r2_lo, r1_lo, r1_hi); \
  float nvH = fmaf(uH, uH, mnH); \
  float sh1 = dpp_shr1_old(r1_hi, (QC)); \
  (QC) = dpp_shl1((QC)); \
  float uL  = dy_lo - (XLO); \
  float mnL = min3f(SH2, sh1, r1_lo); \
  float nvL = fmaf(uL, uL, mnL); \
  pb##K = nvH; \
  if ((K) == 12) { if (cc == 63) ans = nvH; } \
  SH2 = sh1; r2_lo = r1_lo; r1_lo = nvL; r1_hi = nvH; }

#define CHUNK(C, XU, QCU, XP, QCP) { \
  const int cc = (C); \
  if (cc < 63) { \
    { const float2* ip2 = wbase2 + 8 * (cc + 1); \
      float2 a0=ip2[0],a1=ip2[1],a2=ip2[2],a3=ip2[3],a4=ip2[4]; \
      float2 a5=ip2[5],a6=ip2[6],a7=ip2[7],a8=ip2[8]; \
      XP##0=a0.x;  XP##1=a0.y;  XP##2=a1.x;  XP##3=a1.y;  XP##4=a2.x; \
      XP##5=a2.y;  XP##6=a3.x;  XP##7=a3.y;  XP##8=a4.x;  XP##9=a4.y; \
      XP##10=a5.x; XP##11=a5.y; XP##12=a6.x; XP##13=a6.y; XP##14=a7.x; \
      XP##15=a7.y; XP##16=a8.x; XP##17=a8.y; } \
    if (w > 0) { \
      if (fcur < cc + 2) { \
        do { __builtin_amdgcn_s_sleep(1); \
             fcur = __hip_atomic_load(&flagz[w-1], __ATOMIC_ACQUIRE, \
                                      __HIP_MEMORY_SCOPE_WORKGROUP); \
        } while (fcur < cc + 2); \
      } \
      asm volatile("" ::: "memory"); \
      QCP = qb_base[16 * (cc + 1)]; \
      fcur = __hip_atomic_load(&flagz[w-1], __ATOMIC_RELAXED, \
                               __HIP_MEMORY_SCOPE_WORKGROUP); \
    } \
  } \
  PINW18(XU); PINF(QCU); \
  STEP2(0,  QCU, XU##1,  XU##0 ) \
  STEP2(1,  QCU, XU##2,  XU##1 ) \
  STEP2(2,  QCU, XU##3,  XU##2 ) \
  STEP2(3,  QCU, XU##4,  XU##3 ) \
  STEP2(4,  QCU, XU##5,  XU##4 ) \
  STEP2(5,  QCU, XU##6,  XU##5 ) \
  STEP2(6,  QCU, XU##7,  XU##6 ) \
  STEP2(7,  QCU, XU##8,  XU##7 ) \
  STEP2(8,  QCU, XU##9,  XU##8 ) \
  STEP2(9,  QCU, XU##10, XU##9 ) \
  STEP2(10, QCU, XU##11, XU##10) \
  STEP2(11, QCU, XU##12, XU##11) \
  STEP2(12, QCU, XU##13, XU##12) \
  STEP2(13, QCU, XU##14, XU##13) \
  STEP2(14, QCU, XU##15, XU##14) \
  STEP2(15, QCU, XU##16, XU##15) \
  if (w < 3) { \
    if (t == 63) { \
      float* pd = &Mbx[w][16*cc + 2]; \
      pd[0]  = pb0;  pd[1]  = pb1;  pd[2]  = pb2;  pd[3]  = pb3; \
      pd[4]  = pb4;  pd[5]  = pb5;  pd[6]  = pb6;  pd[7]  = pb7; \
      pd[8]  = pb8;  pd[9]  = pb9;  pd[10] = pb10; pd[11] = pb11; \
      pd[12] = pb12; pd[13] = pb13; pd[14] = pb14; pd[15] = pb15; \
    } \
    __hip_atomic_store(&flagz[w], cc + 1, __ATOMIC_RELEASE, \
                       __HIP_MEMORY_SCOPE_WORKGROUP); \
  } }

__global__ __launch_bounds__(256, 1)
void sdtw_kernel(const float* __restrict__ input,
                 const float* __restrict__ target,
                 float* __restrict__ out) {
  const int b   = blockIdx.x;
  const int tid = threadIdx.x;        // 0..255; rows 2*tid, 2*tid+1
  const int t   = tid & 63;           // lane
  const int w   = tid >> 6;           // wave 0..3

  // Mdx[512+f] = dx[f] for f in [0,510]; zero pad elsewhere (780 f2).
  __shared__ __align__(8) float Mdx[1560];
  // Mbx[I][idx] = wave I lane63 nv_hi after step idx-2; row padded to 1092
  // so the conveyor's junk lanes (idx up to 16*63+1+63=1072) stay in-bounds.
  __shared__ __align__(8) float Mbx[3][1092];
  __shared__ int flagz[3];

  const float* __restrict__ inp = input + b * 512;
  const float* __restrict__ tgt = target + b * 512;

  for (int i = tid; i < 1560; i += 256) {
    float v = 0.0f;
    if (i >= 512 && i <= 1022) v = inp[i - 511] - inp[i - 512];
    Mdx[i] = v;
  }
  if (tid < 3) flagz[tid] = 0;
  if (tid < 6) Mbx[tid >> 1][tid & 1] = INF_F;  // prefill idx 0,1 per interface

  // dy for the two owned rows (row i uses dy[i-1] = tgt[i]-tgt[i-1])
  float dy_lo = (tid >= 1) ? (tgt[2*tid] - tgt[2*tid - 1]) : 0.0f;
  float dy_hi = tgt[2*tid + 1] - tgt[2*tid];

  // DP state @ chunk 0: r1 = diag d-1 (INF), r2_lo carries R[0][0]=0 seed.
  float r1_lo = INF_F, r1_hi = INF_F;
  float r2_lo = (tid == 0) ? 0.0f : INF_F;
  float SH2   = INF_F;
  float ans   = INF_F;
  int fcur = 0;

  float xa0,xa1,xa2,xa3,xa4,xa5,xa6,xa7,xa8,xa9;
  float xa10,xa11,xa12,xa13,xa14,xa15,xa16,xa17;
  float xb0,xb1,xb2,xb3,xb4,xb5,xb6,xb7,xb8,xb9;
  float xb10,xb11,xb12,xb13,xb14,xb15,xb16,xb17;
  float qca = INF_F, qcb = INF_F;     // conveyor regs (wave0 keeps INF)
  float pb0,pb1,pb2,pb3,pb4,pb5,pb6,pb7;
  float pb8,pb9,pb10,pb11,pb12,pb13,pb14,pb15;

  const float2* wbase2 = ((const float2*)Mdx) + (256 - tid);
  const float* qb_base = &Mbx[(w > 0) ? (w - 1) : 0][1 + t];

  __syncthreads();                    // staging + flag init visible

  // chunk-0 window
  { const float2* ip2 = wbase2;
    float2 a0=ip2[0],a1=ip2[1],a2=ip2[2],a3=ip2[3],a4=ip2[4];
    float2 a5=ip2[5],a6=ip2[6],a7=ip2[7],a8=ip2[8];
    xa0=a0.x;  xa1=a0.y;  xa2=a1.x;  xa3=a1.y;  xa4=a2.x;
    xa5=a2.y;  xa6=a3.x;  xa7=a3.y;  xa8=a4.x;  xa9=a4.y;
    xa10=a5.x; xa11=a5.y; xa12=a6.x; xa13=a6.y; xa14=a7.x;
    xa15=a7.y; xa16=a8.x; xa17=a8.y; }
  // chunk-0 conveyor: wait for producer lead (2 chunks; 4 for wave3 so
  // the faster non-producing wave never re-converges onto wave2), then
  // load and sample fcur for the in-loop fast path.
  if (w > 0) {
    const int need0 = (w == 3) ? 4 : 2;
    do { __builtin_amdgcn_s_sleep(1);
         fcur = __hip_atomic_load(&flagz[w-1], __ATOMIC_ACQUIRE,
                                  __HIP_MEMORY_SCOPE_WORKGROUP);
    } while (fcur < need0);
    asm volatile("" ::: "memory");
    qca = qb_base[0];
  }

#pragma unroll 1
  for (int c = 0; c < 64; c += 2) {
    CHUNK(c,     xa, qca, xb, qcb)
    CHUNK(c + 1, xb, qcb, xa, qca)
  }

  // ans captured at cc=63, K=12 (step 1020, diag 1022) on row 511 = tid 255 hi
  if (tid == 255) {
    atomicAdd(out, ans * (1.0f / 64.0f));
  }
}

extern "C" void kernel_launch(void* const* d_in, const int* in_sizes, int n_in,
                              void* d_out, int out_size, void* d_ws, size_t ws_size,
                              hipStream_t stream) {
  const float* input  = (const float*)d_in[0];
  const float* target = (const float*)d_in[1];
  float* out = (float*)d_out;

  hipMemsetAsync(out, 0, sizeof(float), stream);
  sdtw_kernel<<<64, 256, 0, stream>>>(input, target, out);
}